// Round 1
// baseline (703.616 us; speedup 1.0000x reference)
//
#include <hip/hip_runtime.h>
#include <cfloat>

#define W 512
#define H 512
#define B 4
#define HW (W*H)
#define NTOT (B*HW)
#define CFEAT 128
#define K 512
#define NBINS 512
#define CAP 49152
#define CNT_STRIDE 16
#define NSEL_CAP 2048

// ---------------- init ----------------
__global__ void zero_ws_k(unsigned* __restrict__ hist, int* __restrict__ count) {
    int i = blockIdx.x * blockDim.x + threadIdx.x;
    if (i < B * NBINS) hist[i] = 0u;
    if (i < B) count[i * CNT_STRIDE] = 0;
}

// ---------------- fully fused NMS: score + 5 pools + mask + compact + hist ----
// Tile 32x32 output, halo 15 -> 62x62 staged scores. All pool stages in LDS.
// Stage regions (62-grid coords):  A: mask_init on [3,58]^2
//   B1: supp0 on [6,55]^2   B2: mask|=new0 on [9,52]^2
//   C1: supp1 on [12,49]^2  C2: final mask on [15,46]^2 (= the 32x32 center)
__global__ __launch_bounds__(256) void nms_fused_k(
    const float* __restrict__ bev, const float* __restrict__ raw,
    float* __restrict__ out_scores, unsigned* __restrict__ maskbits,
    float* __restrict__ cval, int* __restrict__ cidx,
    int* __restrict__ count, unsigned* __restrict__ hist) {
    __shared__ float SS[62 * 62];   // scores (persistent)
    __shared__ float ST[62 * 62];   // separable-pool temp (reused 5x)
    __shared__ float SM[56 * 56];   // mask, offset 3
    __shared__ float SP[50 * 50];   // supp0 (offset 6), then supp1 (offset 12, 38x38)
    __shared__ int lcount, lbase;

    const int b = blockIdx.z;
    const int gx0 = blockIdx.x * 32 - 15;
    const int gy0 = blockIdx.y * 32 - 15;
    const int t = threadIdx.x;
    const float* raw_b = raw + b * HW;
    const float* gdr_b = bev + (b * 7 + 2) * HW;

    // load 62x62 scores = raw * (guider > 0), 0 outside image
    for (int idx = t; idx < 62 * 62; idx += 256) {
        int y = idx / 62, x = idx - y * 62;
        int gx = gx0 + x, gy = gy0 + y;
        float v = 0.f;
        if ((unsigned)gx < (unsigned)W && (unsigned)gy < (unsigned)H) {
            int g = (gy << 9) + gx;
            v = gdr_b[g] > 0.f ? raw_b[g] : 0.f;
        }
        SS[idx] = v;
    }
    __syncthreads();

#define HMAX7(PTR, STRIDE) ({ const float* _r = (PTR); \
    float _m = fmaxf(fmaxf(fmaxf(_r[-3*(STRIDE)], _r[-2*(STRIDE)]), fmaxf(_r[-(STRIDE)], _r[0])), \
                     fmaxf(fmaxf(_r[(STRIDE)], _r[2*(STRIDE)]), _r[3*(STRIDE)])); _m; })

    // ---- Stage A ---- h: rows [0,61] x cols [3,58]
    for (int idx = t; idx < 62 * 56; idx += 256) {
        int y = idx / 56, x = 3 + (idx - (idx / 56) * 56);
        ST[y * 62 + x] = HMAX7(SS + y * 62 + x, 1);
    }
    __syncthreads();
    // v + eq: [3,58]^2 -> SM
    for (int idx = t; idx < 56 * 56; idx += 256) {
        int y = 3 + idx / 56, x = 3 + (idx % 56);
        float m = HMAX7(ST + y * 62 + x, 62);
        int gx = gx0 + x, gy = gy0 + y;
        bool inb = (unsigned)gx < (unsigned)W && (unsigned)gy < (unsigned)H;
        SM[(y - 3) * 56 + (x - 3)] = (inb && SS[y * 62 + x] == m) ? 1.f : 0.f;
    }
    __syncthreads();

    // ---- Stage B1: supp0 ---- h: rows [3,58] x cols [6,55]
    for (int idx = t; idx < 56 * 50; idx += 256) {
        int y = 3 + idx / 50, x = 6 + (idx % 50);
        ST[y * 62 + x] = HMAX7(SM + (y - 3) * 56 + (x - 3), 1);
    }
    __syncthreads();
    for (int idx = t; idx < 50 * 50; idx += 256) {
        int y = 6 + idx / 50, x = 6 + (idx % 50);
        float m = HMAX7(ST + y * 62 + x, 62);
        SP[(y - 6) * 50 + (x - 6)] = m > 0.f ? 1.f : 0.f;
    }
    __syncthreads();

    // ---- Stage B2: mask |= new0 ---- h: rows [6,55] x cols [9,52], src = supp0?0:scores
    for (int idx = t; idx < 50 * 44; idx += 256) {
        int y = 6 + idx / 44, x = 9 + (idx % 44);
        float m = -FLT_MAX;
#pragma unroll
        for (int dx = -3; dx <= 3; ++dx) {
            int xx = x + dx;
            float s = SP[(y - 6) * 50 + (xx - 6)] > 0.f ? 0.f : SS[y * 62 + xx];
            m = fmaxf(m, s);
        }
        ST[y * 62 + x] = m;
    }
    __syncthreads();
    for (int idx = t; idx < 44 * 44; idx += 256) {
        int y = 9 + idx / 44, x = 9 + (idx % 44);
        float m = HMAX7(ST + y * 62 + x, 62);
        float sup = SP[(y - 6) * 50 + (x - 6)];
        float ss = sup > 0.f ? 0.f : SS[y * 62 + x];
        bool nm = (ss == m) && (sup == 0.f);
        int gx = gx0 + x, gy = gy0 + y;
        bool inb = (unsigned)gx < (unsigned)W && (unsigned)gy < (unsigned)H;
        int mi = (y - 3) * 56 + (x - 3);
        SM[mi] = (SM[mi] > 0.f || (nm && inb)) ? 1.f : 0.f;
    }
    __syncthreads();

    // ---- Stage C1: supp1 (stored in SP at offset 12, pitch 38) ----
    for (int idx = t; idx < 44 * 38; idx += 256) {
        int y = 9 + idx / 38, x = 12 + (idx % 38);
        ST[y * 62 + x] = HMAX7(SM + (y - 3) * 56 + (x - 3), 1);
    }
    __syncthreads();
    for (int idx = t; idx < 38 * 38; idx += 256) {
        int y = 12 + idx / 38, x = 12 + (idx % 38);
        float m = HMAX7(ST + y * 62 + x, 62);
        SP[(y - 12) * 38 + (x - 12)] = m > 0.f ? 1.f : 0.f;  // supp0 dead, reuse
    }
    __syncthreads();

    // ---- Stage C2: final ---- h: rows [12,49] x cols [15,46], src = supp1?0:scores
    for (int idx = t; idx < 38 * 32; idx += 256) {
        int y = 12 + idx / 32, x = 15 + (idx % 32);
        float m = -FLT_MAX;
#pragma unroll
        for (int dx = -3; dx <= 3; ++dx) {
            int xx = x + dx;
            float s = SP[(y - 12) * 38 + (xx - 12)] > 0.f ? 0.f : SS[y * 62 + xx];
            m = fmaxf(m, s);
        }
        ST[y * 62 + x] = m;
    }
    __syncthreads();

    // v + epilogue over the 32x32 center (4 px/thread).
    // Each wave covers exactly 2 rows per q -> mask goes out as ballot bits.
    float vloc[4]; int gloc[4]; int nloc = 0;
#pragma unroll
    for (int q = 0; q < 4; ++q) {
        int idx = t + q * 256;
        int y = 15 + (idx >> 5), x = 15 + (idx & 31);
        float m = HMAX7(ST + y * 62 + x, 62);
        float sup = SP[(y - 12) * 38 + (x - 12)];
        float v = SS[y * 62 + x];
        float ss = sup > 0.f ? 0.f : v;
        bool nm = (ss == m) && (sup == 0.f);
        bool mk = (SM[(y - 3) * 56 + (x - 3)] > 0.f) || nm;
        int gx = gx0 + x, gy = gy0 + y;
        int g = (gy << 9) + gx;
        out_scores[b * HW + g] = v;
        // bitmask write: lane L of the wave holds bit L; lanes 0 and 32 emit
        // the two 32-bit row words (rows are lane<32 / lane>=32).
        unsigned long long bal = __ballot(mk);
        if ((t & 31) == 0)
            maskbits[(b << 13) + (gy << 4) + blockIdx.x] = (unsigned)(bal >> (t & 32));
        if (mk && v > 0.f) { vloc[nloc] = v; gloc[nloc] = g; ++nloc; }
    }
    if (t == 0) lcount = 0;
    __syncthreads();
    int p0 = nloc ? atomicAdd(&lcount, nloc) : 0;
    __syncthreads();
    if (t == 0) lbase = lcount ? atomicAdd(&count[b * CNT_STRIDE], lcount) : 0;
    __syncthreads();
    for (int j = 0; j < nloc; ++j) {
        int p = lbase + p0 + j;
        float v = vloc[j];
        if (p < CAP) { cval[b * CAP + p] = v; cidx[b * CAP + p] = gloc[j]; }
        unsigned bin = (unsigned)(v * (float)NBINS);
        if (bin > (unsigned)(NBINS - 1)) bin = NBINS - 1;
        atomicAdd(&hist[b * NBINS + bin], 1u);
    }
#undef HMAX7
}

// ---------------- per-batch exact top-K (value desc, idx asc) ----------------
// Coarse 512-bin hist -> parallel suffix scan -> threshold bin -> gather
// candidates >= threshold -> exact rank via broadcast sweep over 64-bit keys.
__global__ __launch_bounds__(512) void select_k(
    const float* __restrict__ cval, const int* __restrict__ cidx,
    const int* __restrict__ count, const unsigned* __restrict__ hist,
    const float* __restrict__ scores, const unsigned* __restrict__ maskbits,
    const float* __restrict__ bev,
    float* __restrict__ out_kpts, float* __restrict__ out_pix, int* __restrict__ topk_idx) {
    __shared__ unsigned long long skey[NSEL_CAP];
    __shared__ unsigned suf[NBINS];
    __shared__ int final_idx[K];
    __shared__ int nsel_s, tbin_s;

    int b = blockIdx.x, t = threadIdx.x;
    int total = count[b * CNT_STRIDE];
    if (total > CAP) total = CAP;

    suf[t] = hist[(b << 9) + t];
    if (t == 0) { nsel_s = 0; tbin_s = 0; }
    __syncthreads();

    // inclusive suffix sum: suf[t] = sum_{j>=t} hist[j]   (9 Hillis-Steele steps)
    for (int off = 1; off < NBINS; off <<= 1) {
        unsigned add = (t + off < NBINS) ? suf[t + off] : 0u;
        __syncthreads();
        suf[t] += add;
        __syncthreads();
    }
    // threshold bin: largest t with suf[t] >= K (0 if total <= K)
    if (total > K) {
        unsigned s0 = suf[t];
        unsigned s1 = (t < NBINS - 1) ? suf[t + 1] : 0u;
        if (s0 >= (unsigned)K && (t == NBINS - 1 || s1 < (unsigned)K)) tbin_s = t;
    }
    __syncthreads();
    int tb = tbin_s;

    // gather candidates >= threshold bin as 64-bit sort keys:
    // key = (float bits << 32) | ~idx  -> key desc == (value desc, idx asc)
    for (int i = t; i < total; i += 512) {
        float v = cval[b * CAP + i];
        int bin = (int)(v * (float)NBINS); if (bin > NBINS - 1) bin = NBINS - 1;
        if (bin >= tb) {
            int p = atomicAdd(&nsel_s, 1);
            if (p < NSEL_CAP)
                skey[p] = ((unsigned long long)__float_as_uint(v) << 32)
                        | (unsigned)(~cidx[b * CAP + i]);
        }
    }
    __syncthreads();
    int ns = nsel_s < NSEL_CAP ? nsel_s : NSEL_CAP;
    int valid = total < K ? total : K;

    // exact rank: broadcast sweep (all lanes read the same skey[j] -> free LDS broadcast)
    for (int i = t; i < ns; i += 512) {
        unsigned long long ki = skey[i];
        int rank = 0;
        for (int j = 0; j < ns; ++j)
            rank += (skey[j] > ki) ? 1 : 0;
        if (rank < valid) final_idx[rank] = (int)(~(unsigned)ki);
    }
    __syncthreads();

    if (t == 0 && valid < K) {
        int fill = valid;
        for (int flat = 0; fill < K && flat < HW; ++flat) {
            int gy = flat >> 9, gx = flat & (W - 1);
            unsigned wb = maskbits[(b << 13) + (gy << 4) + (gx >> 5)];
            bool cand = ((wb >> (gx & 31)) & 1u) && (scores[b * HW + flat] > 0.f);
            if (!cand) final_idx[fill++] = flat;
        }
    }
    __syncthreads();

    int flat = final_idx[t];
    int u = flat >> 9, v = flat & (W - 1);
    float p0 = bev[((b * 7 + 3) << 18) + flat];
    float p1 = bev[((b * 7 + 4) << 18) + flat];
    int kb = b * K + t;
    out_kpts[kb * 4 + 0] = p0;
    out_kpts[kb * 4 + 1] = p1;
    out_kpts[kb * 4 + 2] = 0.f;
    out_kpts[kb * 4 + 3] = 1.f;
    out_pix[kb * 2 + 0] = (float)u;
    out_pix[kb * 2 + 1] = (float)v;
    topk_idx[kb] = flat;
}

// ---------------- feature gather ----------------
__global__ __launch_bounds__(512) void gather_k(const float* __restrict__ feat,
                                                const int* __restrict__ topk_idx,
                                                float* __restrict__ out) {
    int c = blockIdx.x, b = blockIdx.y, k = threadIdx.x;
    int flat = topk_idx[b * K + k];
    out[(b * CFEAT + c) * K + k] = feat[((b * CFEAT + c) << 18) + flat];
}

extern "C" void kernel_launch(void* const* d_in, const int* in_sizes, int n_in,
                              void* d_out, int out_size, void* d_ws, size_t ws_size,
                              hipStream_t stream) {
    const float* bev  = (const float*)d_in[0];
    const float* raw  = (const float*)d_in[1];
    const float* feat = (const float*)d_in[2];

    float* out = (float*)d_out;
    float* out_scores = out;
    float* out_kpts   = out + NTOT;
    float* out_feas   = out + NTOT + B * K * 4;
    float* out_pix    = out + NTOT + B * K * 4 + B * CFEAT * K;

    char* w = (char*)d_ws;
    unsigned* maskbits = (unsigned*)(w);                               // 128 KB (B*512*16 u32)
    unsigned* hist     = (unsigned*)(w + (128u << 10));                // 8 KB (B*512 u32)
    int*      count    = (int*)(w + (136u << 10));                     // 256 B
    float*    cval     = (float*)(w + (136u << 10) + 256);
    int*      cidx     = (int*)(w + (136u << 10) + 256 + B * CAP * 4);
    int*      topk     = (int*)(w + (136u << 10) + 256 + 2u * B * CAP * 4);

    zero_ws_k<<<(B * NBINS + 255) / 256, 256, 0, stream>>>(hist, count);
    nms_fused_k<<<dim3(W / 32, H / 32, B), 256, 0, stream>>>(
        bev, raw, out_scores, maskbits, cval, cidx, count, hist);
    select_k<<<B, 512, 0, stream>>>(cval, cidx, count, hist, out_scores, maskbits, bev,
                                    out_kpts, out_pix, topk);
    gather_k<<<dim3(CFEAT, B), 512, 0, stream>>>(feat, topk, out_feas);
}